// Round 1
// baseline (173.945 us; speedup 1.0000x reference)
//
#include <hip/hip_runtime.h>
#include <hip/hip_bf16.h>

// CFAR via separable box sums.
// Reference: allsum = box321(x); front = box161(x);
//            out = (front/FRONT_DIV) / ((allsum-front)/BG_AREA)
// GUARD=80, BG=80 -> CFAR_UNITS=321 (half 160), GUARD_UNITS=161 (half 80)
// BG_AREA = 321^2-161^2 = 77120 ; FRONT_DIV = 161^2*1.8 = 46657.8

#define IMG 4
#define H 1024
#define W 1024

// ---------------- Kernel A: horizontal box sums (both widths) ---------------
// One wave (64 lanes) per row. Lane loads 16 contiguous floats (4x float4),
// intra-lane serial scan, wave shuffle-scan of lane totals, prefix -> LDS.
// Phase 2: lane k-strided column ownership (c = lane + 64k) for conflict-free
// LDS reads and perfectly coalesced global writes.
__global__ __launch_bounds__(256) void hbox_kernel(const float* __restrict__ x,
                                                   float* __restrict__ h161,
                                                   float* __restrict__ h321) {
    __shared__ float P[4][W];
    const int wave = threadIdx.x >> 6;
    const int lane = threadIdx.x & 63;
    const int row  = (blockIdx.x << 2) + wave;   // 0..4095 (flat over images)

    const float4* xr = reinterpret_cast<const float4*>(x + (size_t)row * W);
    float v[16];
    {
        float4 a0 = xr[(lane << 2) + 0];
        float4 a1 = xr[(lane << 2) + 1];
        float4 a2 = xr[(lane << 2) + 2];
        float4 a3 = xr[(lane << 2) + 3];
        v[0]=a0.x; v[1]=a0.y; v[2]=a0.z; v[3]=a0.w;
        v[4]=a1.x; v[5]=a1.y; v[6]=a1.z; v[7]=a1.w;
        v[8]=a2.x; v[9]=a2.y; v[10]=a2.z; v[11]=a2.w;
        v[12]=a3.x; v[13]=a3.y; v[14]=a3.z; v[15]=a3.w;
    }
    // intra-lane inclusive scan
    float s = 0.f;
#pragma unroll
    for (int j = 0; j < 16; ++j) { s += v[j]; v[j] = s; }
    // wave inclusive scan of lane totals (wave = 64)
    float t = s;
#pragma unroll
    for (int d = 1; d < 64; d <<= 1) {
        float u = __shfl_up(t, d, 64);
        if (lane >= d) t += u;
    }
    const float off = t - s;   // exclusive prefix of lane totals
#pragma unroll
    for (int j = 0; j < 16; ++j) v[j] += off;

    float4* Pr = reinterpret_cast<float4*>(P[wave]);
    Pr[(lane << 2) + 0] = make_float4(v[0], v[1], v[2], v[3]);
    Pr[(lane << 2) + 1] = make_float4(v[4], v[5], v[6], v[7]);
    Pr[(lane << 2) + 2] = make_float4(v[8], v[9], v[10], v[11]);
    Pr[(lane << 2) + 3] = make_float4(v[12], v[13], v[14], v[15]);
    __syncthreads();

    const float* Pw = P[wave];
    float* o161 = h161 + (size_t)row * W;
    float* o321 = h321 + (size_t)row * W;
#pragma unroll
    for (int k = 0; k < 16; ++k) {
        const int c = lane + (k << 6);
        const int hi1 = min(c + 80, W - 1);
        const int lo1 = c - 81;
        float s1 = Pw[hi1] - (lo1 >= 0 ? Pw[lo1] : 0.f);
        const int hi3 = min(c + 160, W - 1);
        const int lo3 = c - 161;
        float s3 = Pw[hi3] - (lo3 >= 0 ? Pw[lo3] : 0.f);
        o161[c] = s1;
        o321[c] = s3;
    }
}

// --------------- Kernel B: vertical sliding sums + final math ---------------
// One thread per (image, column, 32-row segment). Sliding windows in fp32.
// 512 blocks x 256 threads -> 2 blocks/CU, 8 waves/CU.
#define RSEG 32

__global__ __launch_bounds__(256) void vbox_kernel(const float* __restrict__ h161,
                                                   const float* __restrict__ h321,
                                                   float* __restrict__ out) {
    const int b    = blockIdx.x;
    const int img  = b >> 7;          // 128 blocks per image
    const int b7   = b & 127;
    const int seg  = b7 >> 2;         // 32 segments of 32 rows
    const int cblk = b7 & 3;          // 4 column blocks of 256
    const int col  = (cblk << 8) + threadIdx.x;
    const int r0   = seg << 5;

    const size_t base = ((size_t)img << 20) + col;
    const float* p1 = h161 + base;
    const float* p3 = h321 + base;
    float*       po = out  + base;

    const float INV_BG = 1.0f / 77120.0f;
    const float INV_FD = (float)(1.0 / 46657.8);

    // init windows for row r0
    float s3 = 0.f;
    {
        const int lo = max(r0 - 160, 0);
        const int hi = min(r0 + 160, H - 1);
        for (int j = lo; j <= hi; ++j) s3 += p3[j << 10];
    }
    float s1 = 0.f;
    {
        const int lo = max(r0 - 80, 0);
        const int hi = min(r0 + 80, H - 1);
        for (int j = lo; j <= hi; ++j) s1 += p1[j << 10];
    }

    for (int r = r0; r < r0 + RSEG; ++r) {
        const float fr   = s1 * INV_FD;
        const float back = (s3 - s1) * INV_BG;
        po[r << 10] = fr / back;
        // slide window r -> r+1 (conditions are wave-uniform)
        const int add3 = r + 161, sub3 = r - 160;
        if (add3 <= H - 1) s3 += p3[add3 << 10];
        if (sub3 >= 0)     s3 -= p3[sub3 << 10];
        const int add1 = r + 81, sub1 = r - 80;
        if (add1 <= H - 1) s1 += p1[add1 << 10];
        if (sub1 >= 0)     s1 -= p1[sub1 << 10];
    }
}

extern "C" void kernel_launch(void* const* d_in, const int* in_sizes, int n_in,
                              void* d_out, int out_size, void* d_ws, size_t ws_size,
                              hipStream_t stream) {
    const float* x = (const float*)d_in[0];
    float* outp = (float*)d_out;
    // workspace: two 4x1024x1024 fp32 intermediates = 32 MB
    float* h161 = (float*)d_ws;
    float* h321 = h161 + (size_t)IMG * H * W;

    hbox_kernel<<<dim3((IMG * H) / 4), dim3(256), 0, stream>>>(x, h161, h321);
    vbox_kernel<<<dim3(IMG * (H / RSEG) * (W / 256)), dim3(256), 0, stream>>>(h161, h321, outp);
}

// Round 2
// 120.952 us; speedup vs baseline: 1.4381x; 1.4381x over previous
//
#include <hip/hip_runtime.h>
#include <hip/hip_bf16.h>

// CFAR via separable box sums.
// out = SCALE * front / (allsum - front),  SCALE = BG_AREA / FRONT_DIV
// GUARD=80, BG=80 -> CFAR_UNITS=321 (half 160), GUARD_UNITS=161 (half 80)
// BG_AREA = 321^2-161^2 = 77120 ; FRONT_DIV = 161^2*1.8 = 46657.8

#define IMG 4
#define H 1024
#define W 1024
#define RSEG 32

// ---------------- Kernel A: horizontal box sums (both widths) ---------------
// One wave per row: float4 loads -> intra-lane scan -> wave shuffle-scan ->
// prefix row in LDS -> windowed diffs, float4 stores.
__global__ __launch_bounds__(256) void hbox_kernel(const float* __restrict__ x,
                                                   float* __restrict__ h161,
                                                   float* __restrict__ h321) {
    __shared__ float P[4][W];
    const int wave = threadIdx.x >> 6;
    const int lane = threadIdx.x & 63;
    const int row  = (blockIdx.x << 2) + wave;   // 0..4095 flat over images

    const float4* xr = reinterpret_cast<const float4*>(x + (size_t)row * W);
    float v[16];
    {
        float4 a0 = xr[(lane << 2) + 0];
        float4 a1 = xr[(lane << 2) + 1];
        float4 a2 = xr[(lane << 2) + 2];
        float4 a3 = xr[(lane << 2) + 3];
        v[0]=a0.x; v[1]=a0.y; v[2]=a0.z; v[3]=a0.w;
        v[4]=a1.x; v[5]=a1.y; v[6]=a1.z; v[7]=a1.w;
        v[8]=a2.x; v[9]=a2.y; v[10]=a2.z; v[11]=a2.w;
        v[12]=a3.x; v[13]=a3.y; v[14]=a3.z; v[15]=a3.w;
    }
    float s = 0.f;
#pragma unroll
    for (int j = 0; j < 16; ++j) { s += v[j]; v[j] = s; }
    float t = s;
#pragma unroll
    for (int d = 1; d < 64; d <<= 1) {
        float u = __shfl_up(t, d, 64);
        if (lane >= d) t += u;
    }
    const float off = t - s;
#pragma unroll
    for (int j = 0; j < 16; ++j) v[j] += off;

    float4* Pr = reinterpret_cast<float4*>(P[wave]);
    Pr[(lane << 2) + 0] = make_float4(v[0], v[1], v[2], v[3]);
    Pr[(lane << 2) + 1] = make_float4(v[4], v[5], v[6], v[7]);
    Pr[(lane << 2) + 2] = make_float4(v[8], v[9], v[10], v[11]);
    Pr[(lane << 2) + 3] = make_float4(v[12], v[13], v[14], v[15]);
    __syncthreads();

    const float* Pw = P[wave];
    float4* o1 = reinterpret_cast<float4*>(h161 + (size_t)row * W);
    float4* o3 = reinterpret_cast<float4*>(h321 + (size_t)row * W);
#pragma unroll
    for (int k = 0; k < 4; ++k) {
        const int c4 = lane + (k << 6);   // float4 column index
        const int c  = c4 << 2;
        float s1v[4], s3v[4];
#pragma unroll
        for (int i = 0; i < 4; ++i) {
            const int ci = c + i;
            const float h1 = Pw[min(ci + 80, W - 1)];
            const float l1 = (ci - 81 >= 0) ? Pw[ci - 81] : 0.f;
            const float h3 = Pw[min(ci + 160, W - 1)];
            const float l3 = (ci - 161 >= 0) ? Pw[ci - 161] : 0.f;
            s1v[i] = h1 - l1;
            s3v[i] = h3 - l3;
        }
        o1[c4] = make_float4(s1v[0], s1v[1], s1v[2], s1v[3]);
        o3[c4] = make_float4(s3v[0], s3v[1], s3v[2], s3v[3]);
    }
}

// --------------- Kernel B: vertical sliding sums + final math ---------------
// 4 columns per thread (float4). Compile-time trip counts (clamped index +
// 0/1 mask) so the compiler can unroll and keep 8 loads in flight.
// Grid: 512 blocks x 64 threads (img x 32 segs x 4 col-blocks).
__global__ __launch_bounds__(64) void vbox_kernel(const float* __restrict__ h161,
                                                  const float* __restrict__ h321,
                                                  float* __restrict__ out) {
    const int b    = blockIdx.x;
    const int img  = b >> 7;
    const int b7   = b & 127;
    const int seg  = b7 >> 2;         // 0..31
    const int cblk = b7 & 3;          // 0..3
    const int c4   = (cblk << 6) + threadIdx.x;   // float4 column 0..255
    const int r0   = seg << 5;

    const float4* p1 = reinterpret_cast<const float4*>(h161 + ((size_t)img << 20)) + c4;
    const float4* p3 = reinterpret_cast<const float4*>(h321 + ((size_t)img << 20)) + c4;
    float4*       po = reinterpret_cast<float4*>(out  + ((size_t)img << 20)) + c4;

    const float SCALE = 77120.0f / 46657.8f;   // BG_AREA / FRONT_DIV

    float4 s3; s3.x = s3.y = s3.z = s3.w = 0.f;
#pragma unroll 8
    for (int j = 0; j < 321; ++j) {
        const int row = r0 - 160 + j;
        const int rc  = row < 0 ? 0 : (row > H - 1 ? H - 1 : row);
        const float m = (row < 0 || row > H - 1) ? 0.f : 1.f;
        const float4 v = p3[(size_t)rc << 8];
        s3.x = fmaf(v.x, m, s3.x);
        s3.y = fmaf(v.y, m, s3.y);
        s3.z = fmaf(v.z, m, s3.z);
        s3.w = fmaf(v.w, m, s3.w);
    }
    float4 s1; s1.x = s1.y = s1.z = s1.w = 0.f;
#pragma unroll 8
    for (int j = 0; j < 161; ++j) {
        const int row = r0 - 80 + j;
        const int rc  = row < 0 ? 0 : (row > H - 1 ? H - 1 : row);
        const float m = (row < 0 || row > H - 1) ? 0.f : 1.f;
        const float4 v = p1[(size_t)rc << 8];
        s1.x = fmaf(v.x, m, s1.x);
        s1.y = fmaf(v.y, m, s1.y);
        s1.z = fmaf(v.z, m, s1.z);
        s1.w = fmaf(v.w, m, s1.w);
    }

#pragma unroll 4
    for (int i = 0; i < RSEG; ++i) {
        const int r = r0 + i;
        float4 o;
        o.x = SCALE * s1.x / (s3.x - s1.x);
        o.y = SCALE * s1.y / (s3.y - s1.y);
        o.z = SCALE * s1.z / (s3.z - s1.z);
        o.w = SCALE * s1.w / (s3.w - s1.w);
        po[(size_t)r << 8] = o;

        // slide 321-window: add r+161, drop r-160
        {
            const int a = r + 161, d = r - 160;
            const float ma = (a <= H - 1) ? 1.f : 0.f;
            const float md = (d >= 0) ? 1.f : 0.f;
            const float4 va = p3[(size_t)min(a, H - 1) << 8];
            const float4 vd = p3[(size_t)max(d, 0) << 8];
            s3.x += va.x * ma - vd.x * md;
            s3.y += va.y * ma - vd.y * md;
            s3.z += va.z * ma - vd.z * md;
            s3.w += va.w * ma - vd.w * md;
        }
        // slide 161-window: add r+81, drop r-80
        {
            const int a = r + 81, d = r - 80;
            const float ma = (a <= H - 1) ? 1.f : 0.f;
            const float md = (d >= 0) ? 1.f : 0.f;
            const float4 va = p1[(size_t)min(a, H - 1) << 8];
            const float4 vd = p1[(size_t)max(d, 0) << 8];
            s1.x += va.x * ma - vd.x * md;
            s1.y += va.y * ma - vd.y * md;
            s1.z += va.z * ma - vd.z * md;
            s1.w += va.w * ma - vd.w * md;
        }
    }
}

extern "C" void kernel_launch(void* const* d_in, const int* in_sizes, int n_in,
                              void* d_out, int out_size, void* d_ws, size_t ws_size,
                              hipStream_t stream) {
    const float* x = (const float*)d_in[0];
    float* outp = (float*)d_out;
    float* h161 = (float*)d_ws;                      // 16 MB
    float* h321 = h161 + (size_t)IMG * H * W;        // 16 MB

    hbox_kernel<<<dim3((IMG * H) / 4), dim3(256), 0, stream>>>(x, h161, h321);
    vbox_kernel<<<dim3(IMG * (H / RSEG) * (W / 256)), dim3(64), 0, stream>>>(h161, h321, outp);
}

// Round 3
// 96.708 us; speedup vs baseline: 1.7987x; 1.2507x over previous
//
#include <hip/hip_runtime.h>
#include <hip/hip_bf16.h>

// CFAR via separable box sums, vertical pass as hierarchical prefix (SAT-lite).
// out = SCALE * front / (allsum - front),  SCALE = BG_AREA / FRONT_DIV
// BG_AREA = 321^2-161^2 = 77120 ; FRONT_DIV = 161^2*1.8 = 46657.8

#define IMG 4
#define H 1024
#define W 1024
#define PADL 164          // >= 164 so q-164 >= 0; multiple of 4 for float4 align
#define PADR 164
#define ROWLEN (PADL + W + PADR)   // 1352 floats, 16B-aligned stride

// ---------------- Kernel A: horizontal box sums (both widths) ---------------
// One wave per row. Prefix row lives in LDS padded with zeros (left) and the
// row total (right), so phase 2 has NO clamps and uses only aligned
// ds_read_b128 at 16B lane stride (conflict-free optimal pattern).
__global__ __launch_bounds__(256) void hbox_kernel(const float* __restrict__ x,
                                                   float* __restrict__ h161,
                                                   float* __restrict__ h321) {
    __shared__ float P[4][ROWLEN];
    const int wave = threadIdx.x >> 6;
    const int lane = threadIdx.x & 63;
    const int row  = (blockIdx.x << 2) + wave;   // 0..4095 flat over images

    const float4* xr = reinterpret_cast<const float4*>(x + (size_t)row * W);
    float v[16];
    {
        float4 a0 = xr[(lane << 2) + 0];
        float4 a1 = xr[(lane << 2) + 1];
        float4 a2 = xr[(lane << 2) + 2];
        float4 a3 = xr[(lane << 2) + 3];
        v[0]=a0.x; v[1]=a0.y; v[2]=a0.z; v[3]=a0.w;
        v[4]=a1.x; v[5]=a1.y; v[6]=a1.z; v[7]=a1.w;
        v[8]=a2.x; v[9]=a2.y; v[10]=a2.z; v[11]=a2.w;
        v[12]=a3.x; v[13]=a3.y; v[14]=a3.z; v[15]=a3.w;
    }
    float s = 0.f;
#pragma unroll
    for (int j = 0; j < 16; ++j) { s += v[j]; v[j] = s; }
    float t = s;
#pragma unroll
    for (int d = 1; d < 64; d <<= 1) {
        float u = __shfl_up(t, d, 64);
        if (lane >= d) t += u;
    }
    const float off = t - s;
#pragma unroll
    for (int j = 0; j < 16; ++j) v[j] += off;
    const float tot = __shfl(t, 63, 64);   // row total = P[W-1]

    float* Pw = &P[wave][PADL];
    float4* Pr = reinterpret_cast<float4*>(Pw);
    Pr[(lane << 2) + 0] = make_float4(v[0], v[1], v[2], v[3]);
    Pr[(lane << 2) + 1] = make_float4(v[4], v[5], v[6], v[7]);
    Pr[(lane << 2) + 2] = make_float4(v[8], v[9], v[10], v[11]);
    Pr[(lane << 2) + 3] = make_float4(v[12], v[13], v[14], v[15]);
    // pads: left = 0 (prefix before col 0), right = row total (clamped prefix)
#pragma unroll
    for (int j = lane; j < PADL; j += 64) P[wave][j] = 0.f;
#pragma unroll
    for (int j = lane; j < PADR; j += 64) Pw[W + j] = tot;
    __syncthreads();

    float4* o1 = reinterpret_cast<float4*>(h161 + (size_t)row * W);
    float4* o3 = reinterpret_cast<float4*>(h321 + (size_t)row * W);
    const float* Pb = P[wave];
#pragma unroll
    for (int k = 0; k < 4; ++k) {
        const int c4 = lane + (k << 6);      // float4 column index
        const int q  = PADL + (c4 << 2);     // padded float offset, %4 == 0
        const float4 hi1 = *reinterpret_cast<const float4*>(&Pb[q + 80]);
        const float4 A   = *reinterpret_cast<const float4*>(&Pb[q - 84]);
        const float4 Bv  = *reinterpret_cast<const float4*>(&Pb[q - 80]);
        const float4 hi3 = *reinterpret_cast<const float4*>(&Pb[q + 160]);
        const float4 C   = *reinterpret_cast<const float4*>(&Pb[q - 164]);
        const float4 D   = *reinterpret_cast<const float4*>(&Pb[q - 160]);
        float4 s1v, s3v;
        s1v.x = hi1.x - A.w;  s1v.y = hi1.y - Bv.x;
        s1v.z = hi1.z - Bv.y; s1v.w = hi1.w - Bv.z;
        s3v.x = hi3.x - C.w;  s3v.y = hi3.y - D.x;
        s3v.z = hi3.z - D.y;  s3v.w = hi3.w - D.z;
        o1[c4] = s1v;
        o3[c4] = s3v;
    }
}

// ------------- Kernel V1: in-place per-segment column prefix + totals -------
// grid.x = img*seg*colblk (4*32*4=512), grid.y = buffer (0:h161, 1:h321).
__global__ __launch_bounds__(256) void vscan_kernel(float* __restrict__ h161,
                                                    float* __restrict__ h321,
                                                    float* __restrict__ Btot) {
    const int bx  = blockIdx.x;
    const int img = bx >> 7;
    const int b7  = bx & 127;
    const int seg = b7 >> 2;
    const int cb  = b7 & 3;
    const int col = (cb << 8) + threadIdx.x;
    const int r0  = seg << 5;

    float* p = (blockIdx.y ? h321 : h161) + ((size_t)img << 20) + col;
    float sum = 0.f;
#pragma unroll
    for (int jj = 0; jj < 32; jj += 8) {
        float a[8];
#pragma unroll
        for (int j = 0; j < 8; ++j) a[j] = p[(size_t)(r0 + jj + j) << 10];
#pragma unroll
        for (int j = 0; j < 8; ++j) { sum += a[j]; a[j] = sum; }
#pragma unroll
        for (int j = 0; j < 8; ++j) p[(size_t)(r0 + jj + j) << 10] = a[j];
    }
    Btot[((((size_t)blockIdx.y << 2) + img) << 15) + ((size_t)seg << 10) + col] = sum;
}

// ------------- Kernel V2: exclusive scan of segment totals per column ------
// 8192 threads = (buf,img,col); 32 serial segments each.
__global__ __launch_bounds__(256) void segscan_kernel(const float* __restrict__ Btot,
                                                      float* __restrict__ SP) {
    const int t = blockIdx.x * 256 + threadIdx.x;      // (buf*4+img)*1024 + col
    const size_t base = ((size_t)(t >> 10) << 15) + (t & 1023);
    const float* b = Btot + base;
    float* sp = SP + base;
    float off = 0.f;
#pragma unroll
    for (int s = 0; s < 32; ++s) {
        const float v = b[(size_t)s << 10];
        sp[(size_t)s << 10] = off;
        off += v;
    }
}

// ------------- Kernel V3: final — window diffs of column prefixes ----------
// One block per (img, row); thread = one float4 column. P(rho) = P32[rho] + SP[rho>>5].
__global__ __launch_bounds__(256) void final_kernel(const float* __restrict__ h161,
                                                    const float* __restrict__ h321,
                                                    const float* __restrict__ SP,
                                                    float* __restrict__ out) {
    const int img = blockIdx.x >> 10;
    const int r   = blockIdx.x & 1023;
    const int c4  = threadIdx.x;                       // 0..255

    const float4* P1 = reinterpret_cast<const float4*>(h161 + ((size_t)img << 20));
    const float4* P3 = reinterpret_cast<const float4*>(h321 + ((size_t)img << 20));
    // SP float layout: [buf][img][seg][1024] ; as float4: [buf][img][seg][256]
    const float4* SP1 = reinterpret_cast<const float4*>(SP) + ((size_t)img << 13);
    const float4* SP3 = SP1 + ((size_t)4 << 13);

    const int hi1 = min(r + 80, H - 1),  lo1 = r - 81;
    const int hi3 = min(r + 160, H - 1), lo3 = r - 161;

    float4 f  = P1[((size_t)hi1 << 8) + c4];
    float4 fs = SP1[(((size_t)hi1 >> 5) << 8) + c4];
    float fx = f.x + fs.x, fy = f.y + fs.y, fz = f.z + fs.z, fw = f.w + fs.w;
    if (lo1 >= 0) {
        float4 g  = P1[((size_t)lo1 << 8) + c4];
        float4 gs = SP1[(((size_t)lo1 >> 5) << 8) + c4];
        fx -= g.x + gs.x; fy -= g.y + gs.y; fz -= g.z + gs.z; fw -= g.w + gs.w;
    }
    float4 a  = P3[((size_t)hi3 << 8) + c4];
    float4 as = SP3[(((size_t)hi3 >> 5) << 8) + c4];
    float ax = a.x + as.x, ay = a.y + as.y, az = a.z + as.z, aw = a.w + as.w;
    if (lo3 >= 0) {
        float4 g  = P3[((size_t)lo3 << 8) + c4];
        float4 gs = SP3[(((size_t)lo3 >> 5) << 8) + c4];
        ax -= g.x + gs.x; ay -= g.y + gs.y; az -= g.z + gs.z; aw -= g.w + gs.w;
    }

    const float SCALE = (float)(77120.0 / 46657.8);    // BG_AREA / FRONT_DIV
    float4 o;
    o.x = SCALE * fx / (ax - fx);
    o.y = SCALE * fy / (ay - fy);
    o.z = SCALE * fz / (az - fz);
    o.w = SCALE * fw / (aw - fw);
    reinterpret_cast<float4*>(out + ((size_t)img << 20) + ((size_t)r << 10))[c4] = o;
}

extern "C" void kernel_launch(void* const* d_in, const int* in_sizes, int n_in,
                              void* d_out, int out_size, void* d_ws, size_t ws_size,
                              hipStream_t stream) {
    const float* x = (const float*)d_in[0];
    float* outp = (float*)d_out;
    float* h161 = (float*)d_ws;                          // 16 MB
    float* h321 = h161 + (size_t)IMG * H * W;            // 16 MB
    float* Btot = h321 + (size_t)IMG * H * W;            // 1 MB  (2*4*32*1024 fp32)
    float* SPb  = Btot + (size_t)2 * IMG * 32 * W;       // 1 MB

    hbox_kernel<<<dim3((IMG * H) / 4), dim3(256), 0, stream>>>(x, h161, h321);
    vscan_kernel<<<dim3(512, 2), dim3(256), 0, stream>>>(h161, h321, Btot);
    segscan_kernel<<<dim3(32), dim3(256), 0, stream>>>(Btot, SPb);
    final_kernel<<<dim3(IMG * H), dim3(256), 0, stream>>>(h161, h321, SPb, outp);
}